// Round 2
// 153.050 us; speedup vs baseline: 1.3548x; 1.3548x over previous
//
#include <hip/hip_runtime.h>

#define NB 1024
#define LQ 20
#define LD 200
#define E4 32      // 128 floats / 4
#define NK 21
#define NTILE 13   // ceil(208/16) j-tiles of 16 d-cols

typedef __attribute__((ext_vector_type(8))) short bf16x8;   // 8 bf16 = 4 VGPRs
typedef __attribute__((ext_vector_type(4))) float f32x4;

__device__ __forceinline__ short f2bf(float f, float& back) {
    unsigned u = __builtin_bit_cast(unsigned, f);
    unsigned r = (u + 0x7FFFu + ((u >> 16) & 1u)) >> 16;   // RNE
    back = __builtin_bit_cast(float, r << 16);
    return (short)r;
}

__device__ __forceinline__ bf16x8 make_frag(float4 f0, float4 f1, float& sq) {
    bf16x8 v; float bk;
    v[0] = f2bf(f0.x, bk); sq += bk * bk;
    v[1] = f2bf(f0.y, bk); sq += bk * bk;
    v[2] = f2bf(f0.z, bk); sq += bk * bk;
    v[3] = f2bf(f0.w, bk); sq += bk * bk;
    v[4] = f2bf(f1.x, bk); sq += bk * bk;
    v[5] = f2bf(f1.y, bk); sq += bk * bk;
    v[6] = f2bf(f1.z, bk); sq += bk * bk;
    v[7] = f2bf(f1.w, bk); sq += bk * bk;
    return v;
}

__device__ __forceinline__ float fast_exp2(float x) {
#if __has_builtin(__builtin_amdgcn_exp2f)
    return __builtin_amdgcn_exp2f(x);
#else
    return __expf(x * 0.69314718056f);
#endif
}

// phi_k = Ck * 2^(B2*m*mu_k + C2*m^2), Ck = e^{-50 mu_k^2}; k=20 exact (sigma=1e-3).
// For m == 0.0 exactly (padded rows) this adds exactly CK[k] (exp2(0)==1).
__device__ __forceinline__ void rbf_accum(float m, float* S) {
    const float CK[20] = {
        2.52616e-20f, 2.04697e-16f, 6.10193e-13f, 6.69158e-10f, 2.69958e-7f,
        4.00653e-5f,  2.18749e-3f,  4.39369e-2f,  3.24652e-1f,  8.82497e-1f,
        8.82497e-1f,  3.24652e-1f,  4.39369e-2f,  2.18749e-3f,  4.00653e-5f,
        2.69958e-7f,  6.69158e-10f, 6.10193e-13f, 2.04697e-16f, 2.52616e-20f };
    const float a  = -72.13475204f * m * m;      // -50*log2(e) * m^2
    const float bb = 144.26950408f * m;          // 100*log2(e) * m
    #pragma unroll
    for (int k = 0; k < 20; ++k) {
        const float mu = 0.1f * (float)k - 0.95f;
        S[k] = fmaf(CK[k], fast_exp2(fmaf(bb, mu, a)), S[k]);
    }
    const float d = m - 1.0f;
    S[20] += fast_exp2(-721347.5204f * d * d);   // -5e5*log2(e)
}

// One block per (batch, pred). 4 waves; each wave owns j-tiles {w, w+4, w+8, w+12}.
// Barrier-free per-wave pipeline: gather D-tile -> MFMA(D as A, Q as B) ->
// in-register RBF accumulation (i is lane-local under the swapped C layout).
__global__ __launch_bounds__(256, 3) void knrm_main(
    const int* __restrict__ q1, const int* __restrict__ d1,
    const int* __restrict__ q2, const int* __restrict__ d2,
    const float* __restrict__ emb,
    const float* __restrict__ W1, const float* __restrict__ b1,
    const float* __restrict__ W2, const float* __restrict__ b2,
    const float* __restrict__ W3, const float* __restrict__ b3,
    float* __restrict__ logits)     // [2][NB] in workspace
{
    __shared__ float sPhiW[4][LQ][NK];   // per-wave partial S sums, 6.72 KB
    __shared__ float sX[NK];
    __shared__ float sH1[10];
    __shared__ float sH2[5];

    const int bp   = blockIdx.x;
    const int b    = bp & (NB - 1);
    const int pred = bp >> 10;
    const int t    = threadIdx.x;
    const int lane = t & 63, wave = t >> 6;
    const int c    = lane & 15, quad = lane >> 4;
    const int* __restrict__ qi = pred ? q2 : q1;
    const int* __restrict__ di = pred ? d2 : d1;
    const float4* emb4 = (const float4*)emb;

    // ---- prefetch all ids up front (kills the id->gather serial chain) ----
    int qid[2];
    #pragma unroll
    for (int Mt = 0; Mt < 2; ++Mt) {
        int row = Mt * 16 + c; row = row < LQ ? row : LQ - 1;
        qid[Mt] = qi[b * LQ + row];
    }
    int idv[4];
    #pragma unroll
    for (int tt = 0; tt < 4; ++tt) {
        int j = (wave + tt * 4) * 16 + c; j = j < LD ? j : LD - 1;
        idv[tt] = di[b * LD + j];
    }

    // ---- Q fragments (B operand now): cols i = c (Mt0) / 16+c (Mt1) ----
    bf16x8 aF[2][4];
    float rqA = 0.f, rqB = 0.f;
    #pragma unroll
    for (int Mt = 0; Mt < 2; ++Mt) {
        const float4* qb = emb4 + (size_t)(unsigned)qid[Mt] * E4;
        float qs = 0.f;
        #pragma unroll
        for (int ks = 0; ks < 4; ++ks) {
            float4 f0 = qb[ks * 8 + quad * 2];
            float4 f1 = qb[ks * 8 + quad * 2 + 1];
            aF[Mt][ks] = make_frag(f0, f1, qs);
        }
        if (Mt == 1 && c >= LQ - 16) {           // pad q-rows 20..31 -> exact zeros
            #pragma unroll
            for (int ks = 0; ks < 4; ++ks) aF[Mt][ks] = (bf16x8)0;
            qs = 0.f;
        }
        qs += __shfl_xor(qs, 16);                // sum k-chunks across quads
        qs += __shfl_xor(qs, 32);
        const float rq = rsqrtf(qs + 1e-6f);
        if (Mt == 0) rqA = rq; else rqB = rq;
    }

    // ---- per-lane RBF accumulators: i=c (S0), i=16+c (S1, used when c<4) ----
    float S0[NK], S1[NK];
    #pragma unroll
    for (int k = 0; k < NK; ++k) { S0[k] = 0.f; S1[k] = 0.f; }

    #pragma unroll
    for (int tt = 0; tt < 4; ++tt) {
        const int tile = wave + tt * 4;          // wave-uniform
        if (tile >= NTILE) break;

        // gather 16 d-rows (lane c owns row tile*16+c; quads split the 128 dims)
        const float4* db = emb4 + (size_t)(unsigned)idv[tt] * E4;
        bf16x8 bF[4];
        float dsq = 0.f;
        #pragma unroll
        for (int ks = 0; ks < 4; ++ks) {
            float4 f0 = db[ks * 8 + quad * 2];
            float4 f1 = db[ks * 8 + quad * 2 + 1];
            bF[ks] = make_frag(f0, f1, dsq);
        }
        if (tile * 16 + c >= LD) {               // pad d-rows -> exact zeros => m==0
            #pragma unroll
            for (int ks = 0; ks < 4; ++ks) bF[ks] = (bf16x8)0;
            dsq = 0.f;
        }
        dsq += __shfl_xor(dsq, 16);
        dsq += __shfl_xor(dsq, 32);
        const float rdc = rsqrtf(dsq + 1e-6f);   // rd for row tile*16+c (all quads)
        float rdv[4];
        #pragma unroll
        for (int r = 0; r < 4; ++r) rdv[r] = __shfl(rdc, quad * 4 + r);

        // MFMA with swapped operands: C row = d-col j (quad*4+r), C col = q-row i (c)
        f32x4 acc0 = {0.f, 0.f, 0.f, 0.f};
        f32x4 acc1 = {0.f, 0.f, 0.f, 0.f};
        #pragma unroll
        for (int ks = 0; ks < 4; ++ks) {
            acc0 = __builtin_amdgcn_mfma_f32_16x16x32_bf16(bF[ks], aF[0][ks], acc0, 0, 0, 0);
            acc1 = __builtin_amdgcn_mfma_f32_16x16x32_bf16(bF[ks], aF[1][ks], acc1, 0, 0, 0);
        }

        // normalize + RBF straight from registers (j-sum is lane-local)
        #pragma unroll
        for (int r = 0; r < 4; ++r) {
            rbf_accum(acc0[r] * rdv[r] * rqA, S0);
            rbf_accum(acc1[r] * rdv[r] * rqB, S1);
        }
    }

    // ---- fold the 4 j-subsets held by the 4 quads; publish per-wave sums ----
    #pragma unroll
    for (int k = 0; k < NK; ++k) {
        S0[k] += __shfl_xor(S0[k], 16);
        S0[k] += __shfl_xor(S0[k], 32);
        S1[k] += __shfl_xor(S1[k], 16);
        S1[k] += __shfl_xor(S1[k], 32);
    }
    if (quad == 0) {
        #pragma unroll
        for (int k = 0; k < NK; ++k) sPhiW[wave][c][k] = S0[k];
    } else if (quad == 1 && c < LQ - 16) {
        #pragma unroll
        for (int k = 0; k < NK; ++k) sPhiW[wave][16 + c][k] = S1[k];
    }
    __syncthreads();

    // ---- log1p + sum over i; subtract the 8 padded-j rows (each added CK[k]) ----
    if (t < NK) {
        const float mu_t = 0.1f * (float)t - 0.95f;
        const float pad  = (t < 20) ? 8.0f * fast_exp2(-72.13475204f * mu_t * mu_t) : 0.0f;
        float s = 0.f;
        #pragma unroll
        for (int i = 0; i < LQ; ++i) {
            const float v = sPhiW[0][i][t] + sPhiW[1][i][t]
                          + sPhiW[2][i][t] + sPhiW[3][i][t] - pad;
            s += __logf(1.0f + v);
        }
        sX[t] = fmaxf(s, 0.f);   // relu (guards tiny negative from pad cancellation)
    }
    __syncthreads();

    if (t < 10) {
        float v = b1[t];
        #pragma unroll
        for (int k = 0; k < NK; ++k) v += W1[t * NK + k] * sX[k];
        sH1[t] = fmaxf(v, 0.f);
    }
    __syncthreads();

    if (t < 5) {
        float v = b2[t];
        #pragma unroll
        for (int k = 0; k < 10; ++k) v += W2[t * 10 + k] * sH1[k];
        sH2[t] = fmaxf(v, 0.f);
    }
    __syncthreads();

    if (t == 0) {
        float v = b3[0];
        #pragma unroll
        for (int k = 0; k < 5; ++k) v += W3[k] * sH2[k];
        logits[pred * NB + b] = v;
    }
}

__global__ void knrm_combine(const float* __restrict__ logits, float* __restrict__ out)
{
    const int b = blockIdx.x * blockDim.x + threadIdx.x;
    if (b < NB) {
        out[b] = 1.0f / (1.0f + __expf(logits[NB + b] - logits[b]));
    }
}

extern "C" void kernel_launch(void* const* d_in, const int* in_sizes, int n_in,
                              void* d_out, int out_size, void* d_ws, size_t ws_size,
                              hipStream_t stream) {
    float* logits = (float*)d_ws;   // 2*NB floats
    knrm_main<<<2 * NB, 256, 0, stream>>>(
        (const int*)d_in[0], (const int*)d_in[1],
        (const int*)d_in[2], (const int*)d_in[3],
        (const float*)d_in[4],
        (const float*)d_in[5], (const float*)d_in[6],
        (const float*)d_in[7], (const float*)d_in[8],
        (const float*)d_in[9], (const float*)d_in[10],
        logits);
    knrm_combine<<<(NB + 255) / 256, 256, 0, stream>>>(logits, (float*)d_out);
}

// Round 3
// 148.331 us; speedup vs baseline: 1.3979x; 1.0318x over previous
//
#include <hip/hip_runtime.h>

#define NB 1024
#define LQ 20
#define LD 200
#define E4 32      // 128 floats / 4
#define NK 21
#define NTILE 13   // ceil(208/16) j-tiles of 16 d-cols

typedef __attribute__((ext_vector_type(8))) short bf16x8;   // 8 bf16 = 4 VGPRs
typedef __attribute__((ext_vector_type(4))) float f32x4;

__device__ __forceinline__ short f2bf(float f, float& back) {
    unsigned u = __builtin_bit_cast(unsigned, f);
    unsigned r = (u + 0x7FFFu + ((u >> 16) & 1u)) >> 16;   // RNE
    back = __builtin_bit_cast(float, r << 16);
    return (short)r;
}

__device__ __forceinline__ bf16x8 make_frag(float4 f0, float4 f1, float& sq) {
    bf16x8 v; float bk;
    v[0] = f2bf(f0.x, bk); sq += bk * bk;
    v[1] = f2bf(f0.y, bk); sq += bk * bk;
    v[2] = f2bf(f0.z, bk); sq += bk * bk;
    v[3] = f2bf(f0.w, bk); sq += bk * bk;
    v[4] = f2bf(f1.x, bk); sq += bk * bk;
    v[5] = f2bf(f1.y, bk); sq += bk * bk;
    v[6] = f2bf(f1.z, bk); sq += bk * bk;
    v[7] = f2bf(f1.w, bk); sq += bk * bk;
    return v;
}

__device__ __forceinline__ float fast_exp2(float x) {
#if __has_builtin(__builtin_amdgcn_exp2f)
    return __builtin_amdgcn_exp2f(x);
#else
    return __expf(x * 0.69314718056f);
#endif
}

// Gaussian kernel bank via geometric ladder: phi_k = exp(-50 (m-mu_k)^2),
// mu_k = 0.1k - 0.95.  phi_10 computed directly (middle kernel), then
//   up:   phi_{k+1} = phi_k * u,  u_10 = exp(10m - 1),  u *= e^-1 per step
//   down: phi_{k-1} = phi_k * v,  v_10 = exp(-10m),     v *= e^-1 per step
// Walks outward from the middle so underflow->0 only happens in the true
// tails (monotone decreasing past the peak) and is exactly harmless.
// 3 exp2 + ~60 VALU replaces 21 exp2 + ~45 VALU.  k=20 is the exact kernel.
__device__ __forceinline__ void rbf_accum(float m, float* S) {
    const float x = m - 0.05f;                       // m - mu_10
    const float p = fast_exp2(-72.13475204f * x * x);  // phi_10 (= 2^(-50*log2e*x^2))
    S[10] += p;
    float u = fast_exp2(fmaf(m, 14.4269504089f, -1.44269504089f)); // exp(10m-1)
    float q = p;
    #pragma unroll
    for (int k = 11; k <= 19; ++k) {
        q *= u;
        S[k] += q;
        u *= 0.36787944117f;                         // e^-1
    }
    float v = fast_exp2(m * -14.4269504089f);        // exp(-10m)
    q = p;
    #pragma unroll
    for (int k = 9; k >= 0; --k) {
        q *= v;
        S[k] += q;
        v *= 0.36787944117f;
    }
    const float d = m - 1.0f;
    S[20] += fast_exp2(-721347.5204f * d * d);       // exact kernel, sigma=1e-3
}

// One block per (batch, pred). 4 waves; each wave owns j-tiles {w, w+4, w+8, w+12}.
// Barrier-free per-wave pipeline: gather D-tile -> MFMA(D as A, Q as B) ->
// in-register RBF (i lane-local). acc1's 64 useful values (i=16..19) are
// shuffle-redistributed across all 64 lanes: 1 rbf_accum instead of 4.
__global__ __launch_bounds__(256, 3) void knrm_main(
    const int* __restrict__ q1, const int* __restrict__ d1,
    const int* __restrict__ q2, const int* __restrict__ d2,
    const float* __restrict__ emb,
    const float* __restrict__ W1, const float* __restrict__ b1,
    const float* __restrict__ W2, const float* __restrict__ b2,
    const float* __restrict__ W3, const float* __restrict__ b3,
    float* __restrict__ logits)     // [2][NB] in workspace
{
    __shared__ float sPhiW[4][LQ][NK];   // per-wave partial S sums, 6.72 KB
    __shared__ float sX[NK];
    __shared__ float sH1[10];
    __shared__ float sH2[5];

    const int bp   = blockIdx.x;
    const int b    = bp & (NB - 1);
    const int pred = bp >> 10;
    const int t    = threadIdx.x;
    const int lane = t & 63, wave = t >> 6;
    const int c    = lane & 15, quad = lane >> 4;
    const int* __restrict__ qi = pred ? q2 : q1;
    const int* __restrict__ di = pred ? d2 : d1;
    const float4* emb4 = (const float4*)emb;

    // ---- prefetch all ids up front (kills the id->gather serial chain) ----
    int qid[2];
    #pragma unroll
    for (int Mt = 0; Mt < 2; ++Mt) {
        int row = Mt * 16 + c; row = row < LQ ? row : LQ - 1;
        qid[Mt] = qi[b * LQ + row];
    }
    int idv[4];
    #pragma unroll
    for (int tt = 0; tt < 4; ++tt) {
        int j = (wave + tt * 4) * 16 + c; j = j < LD ? j : LD - 1;
        idv[tt] = di[b * LD + j];
    }

    // ---- Q fragments (B operand): cols i = c (Mt0) / 16+c (Mt1) ----
    bf16x8 aF[2][4];
    float rqA = 0.f, rqB = 0.f;
    #pragma unroll
    for (int Mt = 0; Mt < 2; ++Mt) {
        const float4* qb = emb4 + (size_t)(unsigned)qid[Mt] * E4;
        float qs = 0.f;
        #pragma unroll
        for (int ks = 0; ks < 4; ++ks) {
            float4 f0 = qb[ks * 8 + quad * 2];
            float4 f1 = qb[ks * 8 + quad * 2 + 1];
            aF[Mt][ks] = make_frag(f0, f1, qs);
        }
        if (Mt == 1 && c >= LQ - 16) {           // pad q-rows 20..31 -> exact zeros
            #pragma unroll
            for (int ks = 0; ks < 4; ++ks) aF[Mt][ks] = (bf16x8)0;
            qs = 0.f;
        }
        qs += __shfl_xor(qs, 16);                // sum k-chunks across quads
        qs += __shfl_xor(qs, 32);
        const float rq = rsqrtf(qs + 1e-6f);
        if (Mt == 0) rqA = rq; else rqB = rq;
    }

    // ---- per-lane RBF accumulators ----
    // S0: i = c, j = tile*16 + quad*4 + r   (summed over quads at the end)
    // S1: redistributed; lane L owns (i = 16+((L>>2)&3), j = tile*16+(L>>4)*4+(L&3))
    float S0[NK], S1[NK];
    #pragma unroll
    for (int k = 0; k < NK; ++k) { S0[k] = 0.f; S1[k] = 0.f; }

    #pragma unroll
    for (int tt = 0; tt < 4; ++tt) {
        const int tile = wave + tt * 4;          // wave-uniform
        if (tile >= NTILE) break;

        // gather 16 d-rows (lane c owns row tile*16+c; quads split the 128 dims)
        const float4* db = emb4 + (size_t)(unsigned)idv[tt] * E4;
        bf16x8 bF[4];
        float dsq = 0.f;
        #pragma unroll
        for (int ks = 0; ks < 4; ++ks) {
            float4 f0 = db[ks * 8 + quad * 2];
            float4 f1 = db[ks * 8 + quad * 2 + 1];
            bF[ks] = make_frag(f0, f1, dsq);
        }
        if (tile * 16 + c >= LD) {               // pad d-rows -> exact zeros => m==0
            #pragma unroll
            for (int ks = 0; ks < 4; ++ks) bF[ks] = (bf16x8)0;
            dsq = 0.f;
        }
        dsq += __shfl_xor(dsq, 16);
        dsq += __shfl_xor(dsq, 32);
        const float rdc = rsqrtf(dsq + 1e-6f);   // rd for row tile*16+c
        float rdv[4];
        #pragma unroll
        for (int r = 0; r < 4; ++r) rdv[r] = __shfl(rdc, quad * 4 + r);

        // MFMA swapped: C col = lane&15 = q-row i, C row = quad*4+reg = d-col j
        f32x4 acc0 = {0.f, 0.f, 0.f, 0.f};
        f32x4 acc1 = {0.f, 0.f, 0.f, 0.f};
        #pragma unroll
        for (int ks = 0; ks < 4; ++ks) {
            acc0 = __builtin_amdgcn_mfma_f32_16x16x32_bf16(bF[ks], aF[0][ks], acc0, 0, 0, 0);
            acc1 = __builtin_amdgcn_mfma_f32_16x16x32_bf16(bF[ks], aF[1][ks], acc1, 0, 0, 0);
        }

        // acc0: i = c is real for all lanes; 4 rbf per lane
        #pragma unroll
        for (int r = 0; r < 4; ++r)
            rbf_accum(acc0[r] * rdv[r] * rqA, S0);

        // acc1: only cols c<4 real (i=16..19) -> 64 useful values per tile.
        // Redistribute so each lane runs exactly ONE rbf_accum.
        // Lane L takes value (src_lane = (L&48)|((L>>2)&3), reg = L&3).
        float m1[4];
        #pragma unroll
        for (int r = 0; r < 4; ++r) m1[r] = acc1[r] * rdv[r] * rqB;
        const int src = (lane & 48) | ((lane >> 2) & 3);
        const float g0 = __shfl(m1[0], src);
        const float g1 = __shfl(m1[1], src);
        const float g2 = __shfl(m1[2], src);
        const float g3 = __shfl(m1[3], src);
        const int rsel = lane & 3;
        const float mv = (rsel == 0) ? g0 : (rsel == 1) ? g1 : (rsel == 2) ? g2 : g3;
        rbf_accum(mv, S1);
    }

    // ---- reductions ----
    // S0: fold the 4 j-subsets held by the quads (bits 4,5)
    // S1: fold lanes sharing i-bits 2-3 (bits 0,1,4,5)
    #pragma unroll
    for (int k = 0; k < NK; ++k) {
        S0[k] += __shfl_xor(S0[k], 16);
        S0[k] += __shfl_xor(S0[k], 32);
        S1[k] += __shfl_xor(S1[k], 1);
        S1[k] += __shfl_xor(S1[k], 2);
        S1[k] += __shfl_xor(S1[k], 16);
        S1[k] += __shfl_xor(S1[k], 32);
    }
    if (quad == 0) {
        #pragma unroll
        for (int k = 0; k < NK; ++k) sPhiW[wave][c][k] = S0[k];
    }
    if ((lane & 51) == 0) {                       // lanes 0,4,8,12 -> i = 16..19
        #pragma unroll
        for (int k = 0; k < NK; ++k) sPhiW[wave][16 + (lane >> 2)][k] = S1[k];
    }
    __syncthreads();

    // ---- log1p + sum over i; subtract the 8 padded-j rows (each added phi_k(0)) ----
    if (t < NK) {
        const float mu_t = 0.1f * (float)t - 0.95f;
        const float pad  = (t < 20) ? 8.0f * fast_exp2(-72.13475204f * mu_t * mu_t) : 0.0f;
        float s = 0.f;
        #pragma unroll
        for (int i = 0; i < LQ; ++i) {
            const float v = sPhiW[0][i][t] + sPhiW[1][i][t]
                          + sPhiW[2][i][t] + sPhiW[3][i][t] - pad;
            s += __logf(1.0f + v);
        }
        sX[t] = fmaxf(s, 0.f);   // relu (guards tiny negative from pad cancellation)
    }
    __syncthreads();

    if (t < 10) {
        float v = b1[t];
        #pragma unroll
        for (int k = 0; k < NK; ++k) v += W1[t * NK + k] * sX[k];
        sH1[t] = fmaxf(v, 0.f);
    }
    __syncthreads();

    if (t < 5) {
        float v = b2[t];
        #pragma unroll
        for (int k = 0; k < 10; ++k) v += W2[t * 10 + k] * sH1[k];
        sH2[t] = fmaxf(v, 0.f);
    }
    __syncthreads();

    if (t == 0) {
        float v = b3[0];
        #pragma unroll
        for (int k = 0; k < 5; ++k) v += W3[k] * sH2[k];
        logits[pred * NB + b] = v;
    }
}

__global__ void knrm_combine(const float* __restrict__ logits, float* __restrict__ out)
{
    const int b = blockIdx.x * blockDim.x + threadIdx.x;
    if (b < NB) {
        out[b] = 1.0f / (1.0f + __expf(logits[NB + b] - logits[b]));
    }
}

extern "C" void kernel_launch(void* const* d_in, const int* in_sizes, int n_in,
                              void* d_out, int out_size, void* d_ws, size_t ws_size,
                              hipStream_t stream) {
    float* logits = (float*)d_ws;   // 2*NB floats
    knrm_main<<<2 * NB, 256, 0, stream>>>(
        (const int*)d_in[0], (const int*)d_in[1],
        (const int*)d_in[2], (const int*)d_in[3],
        (const float*)d_in[4],
        (const float*)d_in[5], (const float*)d_in[6],
        (const float*)d_in[7], (const float*)d_in[8],
        (const float*)d_in[9], (const float*)d_in[10],
        logits);
    knrm_combine<<<(NB + 255) / 256, 256, 0, stream>>>(logits, (float*)d_out);
}